// Round 22
// baseline (102.275 us; speedup 1.0000x reference)
//
#include <hip/hip_runtime.h>
#include <cstdint>
#include <cstddef>

#define B_  8
#define T_  12
#define N_  250
#define D_  64
#define H_  8
#define HD_ 8

typedef short     bf16x8  __attribute__((ext_vector_type(8)));
typedef float     f32x16  __attribute__((ext_vector_type(16)));
typedef float     f32x4v  __attribute__((ext_vector_type(4)));
typedef unsigned  u32x2   __attribute__((ext_vector_type(2)));
typedef unsigned  u32x4   __attribute__((ext_vector_type(4)));

#if __has_builtin(__builtin_amdgcn_exp2f)
#define EXP2(x) __builtin_amdgcn_exp2f(x)
#else
#define EXP2(x) exp2f(x)
#endif

__device__ __forceinline__ uint16_t f2bf(float f) {
    uint32_t u = __builtin_bit_cast(uint32_t, f);
    uint32_t r = (u + 0x7FFFu + ((u >> 16) & 1u)) >> 16;   // RNE
    return (uint16_t)r;
}

__device__ __forceinline__ float bfLO(unsigned u) {
    return __builtin_bit_cast(float, u << 16);
}
__device__ __forceinline__ float bfHI(unsigned u) {
    return __builtin_bit_cast(float, u & 0xFFFF0000u);
}

// ---------------- Kernel A: QKV projection -> bf16 operand buffers ----------
// qbh/kbh: [bt*8+h][256 rows (250 used)][8] bf16, row-major 16B rows.
// vbh:     [bt*8+h][8 d][256 m]            bf16 (V transposed per head).
__global__ __launch_bounds__(256) void qkv_kernel(
    const float* __restrict__ x,
    const float* __restrict__ Wq, const float* __restrict__ bq,
    const float* __restrict__ Wk, const float* __restrict__ bk,
    const float* __restrict__ Wv, const float* __restrict__ bv,
    uint16_t* __restrict__ qbh, uint16_t* __restrict__ kbh,
    uint16_t* __restrict__ vbh)
{
    __shared__ float WqT[64*64];
    __shared__ float WkT[64*64];
    __shared__ float WvT[64*64];
    __shared__ float xT[4][64][8];

    int tid = threadIdx.x;
    for (int i = tid; i < 4096; i += 256) {
        int d = i >> 6, j = i & 63;
        WqT[j*64 + d] = Wq[i];
        WkT[j*64 + d] = Wk[i];
        WvT[j*64 + d] = Wv[i];
    }
    __syncthreads();

    int wave = tid >> 6, lane = tid & 63;
    int row0 = blockIdx.x * 32 + wave * 8;   // 750*32 = 24000 rows

    #pragma unroll
    for (int rr = 0; rr < 8; ++rr)
        xT[wave][lane][rr] = x[(size_t)(row0 + rr)*64 + lane];

    float accq[8], acck[8], accv[8];
    float bqv = bq[lane], bkv = bk[lane], bvv = bv[lane];
    #pragma unroll
    for (int rr = 0; rr < 8; ++rr) { accq[rr]=bqv; acck[rr]=bkv; accv[rr]=bvv; }

    #pragma unroll 8
    for (int j = 0; j < 64; ++j) {
        float4 xa = *(const float4*)&xT[wave][j][0];
        float4 xb = *(const float4*)&xT[wave][j][4];
        float wq = WqT[j*64 + lane];
        float wk = WkT[j*64 + lane];
        float wv = WvT[j*64 + lane];
        float xr[8] = {xa.x, xa.y, xa.z, xa.w, xb.x, xb.y, xb.z, xb.w};
        #pragma unroll
        for (int rr = 0; rr < 8; ++rr) {
            accq[rr] = fmaf(xr[rr], wq, accq[rr]);
            acck[rr] = fmaf(xr[rr], wk, acck[rr]);
            accv[rr] = fmaf(xr[rr], wv, accv[rr]);
        }
    }

    int h = lane >> 3, dh = lane & 7;
    #pragma unroll
    for (int rr = 0; rr < 8; ++rr) {
        int row = row0 + rr;
        int bt = row / 250;
        int nn = row - bt*250;
        size_t hb = (size_t)(bt*8 + h);
        qbh[(hb*256 + nn)*8 + dh] = f2bf(accq[rr]);
        kbh[(hb*256 + nn)*8 + dh] = f2bf(acck[rr]);
        vbh[(hb*8 + dh)*256 + nn] = f2bf(accv[rr]);
    }
}

// ---------------- Kernel B: MFMA windowed attention (best-measured config) --
// grid = (b,t,ti,ntile) = 2304 blocks x 512 thr (8 waves; wave = head h).
// f32 adj tile in LDS (stride 260), launch_bounds(512,4). Q pre-scaled by
// scale*log2e. hs output bf16. K prologue (load + first QK MFMA) hoisted
// BEFORE __syncthreads so its latency drains under other waves' staging.
__global__ __launch_bounds__(512, 4) void attn_kernel(
    const uint16_t* __restrict__ qbh, const uint16_t* __restrict__ kbh,
    const uint16_t* __restrict__ vbh, const float* __restrict__ adj,
    uint16_t* __restrict__ hs)
{
    __shared__ float alds[32*260];     // [n-local][m], pad 260 for b128 reads

    const float S0e = 0.51006972338f;    // 8^-0.5 * log2(e)
    const float S1e = 0.18033688011f;    // 8^-1   * log2(e)
    const float S2e = 0.06375872168f;    // 8^-1.5 * log2(e)

    int tid  = threadIdx.x;
    int h    = tid >> 6;          // wave id = head
    int lane = tid & 63;
    int ln31 = lane & 31, hi = lane >> 5;

    int idx = blockIdx.x;
    int ntile = idx & 7; idx >>= 3;
    int ti = idx % 3; idx /= 3;
    int t  = idx % 12;
    int b  = idx / 12;

    int t_k = (ti == 2) ? t : (t + 11) % 12;   // cumulative k/v shift
    int t_a = (t + ti + 11) % 12;              // fresh adj shift
    float scale = (ti == 0) ? S0e : (ti == 1) ? S1e : S2e;

    int n0 = ntile * 32;

    // ---- stage adj tile: rows n0..n0+31 (clamped), cols 0..255 (m-pad=0) --
    const float* adjs = adj + (size_t)(b*12 + t_a) * 62500;
    for (int i = tid; i < 8192; i += 512) {
        int row = i >> 8;            // 0..31
        int col = i & 255;           // 0..255
        int nr = n0 + row; nr = nr > 249 ? 249 : nr;
        float v = (col < 250) ? adjs[(size_t)nr*250 + col] : 0.f;
        alds[row*260 + col] = v;
    }

    const uint16_t* qh = qbh + ((size_t)((b*12 + t  )*8 + h) * 256) * 8;
    const uint16_t* kh = kbh + ((size_t)((b*12 + t_k)*8 + h) * 256) * 8;
    const uint16_t* vh = vbh + ((size_t)((b*12 + t_k)*8 + h) * 8) * 256;

    int n  = n0 + ln31;

    bf16x8 qf = *(const bf16x8*)(qh + (size_t)n * 8);
    bf16x8 z8 = {0,0,0,0,0,0,0,0};
    if (hi) qf = z8;               // zeroes QK k=8..15 (B-operand side)

    // pre-scale Q by scale (incl. log2e): s comes out of the MFMA already
    // multiplied, so the inner loop does exp2(s) with no per-element mul.
    {
        const uint16_t* qu = (const uint16_t*)&qf;
        unsigned qw[4];
        #pragma unroll
        for (int e = 0; e < 4; ++e) {
            float q0 = __builtin_bit_cast(float, (uint32_t)qu[2*e]   << 16) * scale;
            float q1 = __builtin_bit_cast(float, (uint32_t)qu[2*e+1] << 16) * scale;
            asm("v_cvt_pk_bf16_f32 %0, %1, %2" : "=v"(qw[e]) : "v"(q0), "v"(q1));
        }
        u32x4 qv = {qw[0], qw[1], qw[2], qw[3]};
        qf = __builtin_bit_cast(bf16x8, qv);
    }

    const uint16_t* vrp = vh + (size_t)(ln31 & 7) * 256;
    const float* arow_l = &alds[ln31*260 + 4*hi];

    f32x16 zc;
    #pragma unroll
    for (int i = 0; i < 16; ++i) zc[i] = 0.f;
    f32x16 acc = zc;
    float zA = 0.f, zB = 0.f;         // split Z chain

    // score pipeline prologue BEFORE the barrier: no LDS dependency, so the
    // K-load latency and first QK MFMA overlap other waves' adj staging.
    bf16x8 kf0 = *(const bf16x8*)(kh + (size_t)ln31 * 8);
    f32x16 s_c = __builtin_amdgcn_mfma_f32_32x32x16_bf16(kf0, qf, zc, 0, 0, 0);

    __syncthreads();                  // adj staging visible

    #pragma unroll
    for (int mt = 0; mt < 8; ++mt) {
        int m0 = mt * 32;

        // issue next K load early; its MFMA sits after the softmax so the
        // L2 latency drains under the exp2/cvt work
        bf16x8 kf_n = z8;
        if (mt < 7)
            kf_n = *(const bf16x8*)(kh + (size_t)(m0 + 32 + ln31) * 8);

        bf16x8 vfa = *(const bf16x8*)(vrp + m0 + hi*8);
        bf16x8 vfb = *(const bf16x8*)(vrp + m0 + 16 + hi*8);

        // adj: 4 vector LDS reads cover the 16 m-values of this lane's regs
        f32x4v av0 = *(const f32x4v*)(arow_l + m0);
        f32x4v av1 = *(const f32x4v*)(arow_l + m0 + 8);
        f32x4v av2 = *(const f32x4v*)(arow_l + m0 + 16);
        f32x4v av3 = *(const f32x4v*)(arow_l + m0 + 24);

        unsigned w[8];
        #pragma unroll
        for (int e = 0; e < 8; ++e) {
            int r0 = 2*e, r1 = 2*e + 1;
            float p0 = EXP2(s_c[r0]);        // scale pre-folded into Q
            float p1 = EXP2(s_c[r1]);
            float av0v = (r0 < 4) ? av0[r0 & 3] : (r0 < 8) ? av1[r0 & 3]
                       : (r0 < 12) ? av2[r0 & 3] : av3[r0 & 3];
            float av1v = (r1 < 4) ? av0[r1 & 3] : (r1 < 8) ? av1[r1 & 3]
                       : (r1 < 12) ? av2[r1 & 3] : av3[r1 & 3];
            if (mt == 7) {   // zero p for m-pad 250..255 (av already 0 in LDS)
                int c0 = (r0 & 3) + 8*(r0 >> 2) + 4*hi;
                int c1 = (r1 & 3) + 8*(r1 >> 2) + 4*hi;
                if (224 + c0 >= 250) p0 = 0.f;
                if (224 + c1 >= 250) p1 = 0.f;
            }
            zA += p0; zB += p1;
            float pa0 = p0 * av0v, pa1 = p1 * av1v;
            asm("v_cvt_pk_bf16_f32 %0, %1, %2"
                : "=v"(w[e]) : "v"(pa0), "v"(pa1));
        }
        // non-volatile pure register ops: data deps preserve order
        asm("v_permlane32_swap_b32 %0, %1" : "+v"(w[2]), "+v"(w[0]));
        asm("v_permlane32_swap_b32 %0, %1" : "+v"(w[3]), "+v"(w[1]));
        asm("v_permlane32_swap_b32 %0, %1" : "+v"(w[6]), "+v"(w[4]));
        asm("v_permlane32_swap_b32 %0, %1" : "+v"(w[7]), "+v"(w[5]));

        u32x4 t1 = {w[0], w[1], w[2], w[3]};
        u32x4 t2 = {w[4], w[5], w[6], w[7]};
        bf16x8 pf1 = __builtin_bit_cast(bf16x8, t1);
        bf16x8 pf2 = __builtin_bit_cast(bf16x8, t2);

        // next-tile QK MFMA overlaps PV on the matrix pipe
        f32x16 s_n = s_c;
        if (mt < 7)
            s_n = __builtin_amdgcn_mfma_f32_32x32x16_bf16(kf_n, qf, zc, 0, 0, 0);

        acc = __builtin_amdgcn_mfma_f32_32x32x16_bf16(vfa, pf1, acc, 0, 0, 0);
        acc = __builtin_amdgcn_mfma_f32_32x32x16_bf16(vfb, pf2, acc, 0, 0, 0);

        s_c = s_n;
    }

    float z = zA + zB;
    float zf = z + __shfl_xor(z, 32);
    float inv = 1.0f / zf;

    if (n < 250) {
        float a0 = acc[0]*inv, a1 = acc[1]*inv;
        float a2 = acc[2]*inv, a3 = acc[3]*inv;
        unsigned w0, w1;
        asm("v_cvt_pk_bf16_f32 %0, %1, %2" : "=v"(w0) : "v"(a0), "v"(a1));
        asm("v_cvt_pk_bf16_f32 %0, %1, %2" : "=v"(w1) : "v"(a2), "v"(a3));
        u32x2 pk = {w0, w1};
        *(u32x2*)(hs + (((size_t)(b*36 + ti*12 + t)*250 + n)*64 + h*8 + hi*4)) = pk;
    }
}

// ---------------- Kernel C: Wd head + residual + LayerNorm ----------------
// hs is bf16: staged as u32 pairs, unpacked to f32 in LDS.
__global__ __launch_bounds__(256) void out_kernel(
    const uint16_t* __restrict__ hsb, const float* __restrict__ x,
    const float* __restrict__ Wd, const float* __restrict__ bd,
    const float* __restrict__ gamma, const float* __restrict__ beta,
    float* __restrict__ out)
{
    __shared__ float hl[36*64];
    __shared__ float xl[12*64];

    int bn = blockIdx.x;
    int n = bn % 250, b = bn / 250;
    int tid = threadIdx.x;

    for (int i = tid; i < 36*32; i += 256) {    // 1152 u32 words (2 bf16 each)
        int tw = i >> 5;          // 0..35
        int dw = i & 31;          // d-pair index 0..31
        uint32_t g = *(const uint32_t*)(hsb +
            ((size_t)(b*36 + tw)*250 + n)*64 + dw*2);
        hl[tw*64 + 2*dw]     = bfLO(g);
        hl[tw*64 + 2*dw + 1] = bfHI(g);
    }
    for (int i = tid; i < 12*64; i += 256) {
        int t = i >> 6, d = i & 63;
        xl[i] = x[((size_t)(b*12 + t)*250 + n)*64 + d];
    }
    __syncthreads();

    int lane = tid & 63, wv = tid >> 6;
    float gg = gamma[lane], bb = beta[lane];

    for (int t = wv; t < 12; t += 4) {
        float acc = bd[t];
        const float* wd = Wd + t*36;
        #pragma unroll
        for (int tw = 0; tw < 36; ++tw)
            acc = fmaf(wd[tw], hl[tw*64 + lane], acc);
        float y = acc + xl[t*64 + lane];

        float s = y, s2 = y*y;
        #pragma unroll
        for (int o = 32; o >= 1; o >>= 1) {
            s  += __shfl_xor(s, o);
            s2 += __shfl_xor(s2, o);
        }
        float mu  = s * 0.015625f;
        float var = s2 * 0.015625f - mu*mu;
        out[((size_t)(b*12 + t)*250 + n)*64 + lane] =
            gg * (y - mu) * rsqrtf(var + 1e-5f) + bb;
    }
}

extern "C" void kernel_launch(void* const* d_in, const int* in_sizes, int n_in,
                              void* d_out, int out_size, void* d_ws, size_t ws_size,
                              hipStream_t stream)
{
    const float* x    = (const float*)d_in[0];
    // d_in[1] = ste : unused by the reference
    const float* adj  = (const float*)d_in[2];
    const float* Wq   = (const float*)d_in[3];
    const float* bq   = (const float*)d_in[4];
    const float* Wk   = (const float*)d_in[5];
    const float* bk   = (const float*)d_in[6];
    const float* Wv   = (const float*)d_in[7];
    const float* bv   = (const float*)d_in[8];
    const float* Wd   = (const float*)d_in[9];
    const float* bd   = (const float*)d_in[10];
    const float* gam  = (const float*)d_in[11];
    const float* bet  = (const float*)d_in[12];
    float* out = (float*)d_out;

    // ws layout (bytes): hs bf16 [9,216,000, region reserved 18,432,000] |
    // qbh | kbh | vbh (bf16, each 3,145,728 B).
    uint16_t* hs  = (uint16_t*)d_ws;
    uint16_t* qbh = (uint16_t*)((char*)d_ws + 18432000);
    uint16_t* kbh = qbh + 1572864;
    uint16_t* vbh = kbh + 1572864;

    qkv_kernel<<<750, 256, 0, stream>>>(x, Wq, bq, Wk, bk, Wv, bv, qbh, kbh, vbh);
    attn_kernel<<<B_*T_*3*8, 512, 0, stream>>>(qbh, kbh, vbh, adj, hs);
    out_kernel<<<B_*N_, 256, 0, stream>>>(hs, x, Wd, bd, gam, bet, out);
}

// Round 23
// 82.332 us; speedup vs baseline: 1.2422x; 1.2422x over previous
//
#include <hip/hip_runtime.h>
#include <cstdint>
#include <cstddef>

#define B_  8
#define T_  12
#define N_  250
#define D_  64
#define H_  8
#define HD_ 8

typedef short     bf16x8  __attribute__((ext_vector_type(8)));
typedef float     f32x16  __attribute__((ext_vector_type(16)));
typedef float     f32x4v  __attribute__((ext_vector_type(4)));
typedef unsigned  u32x2   __attribute__((ext_vector_type(2)));
typedef unsigned  u32x4   __attribute__((ext_vector_type(4)));

#if __has_builtin(__builtin_amdgcn_exp2f)
#define EXP2(x) __builtin_amdgcn_exp2f(x)
#else
#define EXP2(x) exp2f(x)
#endif

__device__ __forceinline__ uint16_t f2bf(float f) {
    uint32_t u = __builtin_bit_cast(uint32_t, f);
    uint32_t r = (u + 0x7FFFu + ((u >> 16) & 1u)) >> 16;   // RNE
    return (uint16_t)r;
}

__device__ __forceinline__ float bfLO(unsigned u) {
    return __builtin_bit_cast(float, u << 16);
}
__device__ __forceinline__ float bfHI(unsigned u) {
    return __builtin_bit_cast(float, u & 0xFFFF0000u);
}

// pack 8 consecutive f32 (from ptr) into a bf16x8 fragment
__device__ __forceinline__ bf16x8 pack8(const float* p) {
    float4 a = *(const float4*)p;
    float4 b = *(const float4*)(p + 4);
    unsigned w0, w1, w2, w3;
    asm("v_cvt_pk_bf16_f32 %0, %1, %2" : "=v"(w0) : "v"(a.x), "v"(a.y));
    asm("v_cvt_pk_bf16_f32 %0, %1, %2" : "=v"(w1) : "v"(a.z), "v"(a.w));
    asm("v_cvt_pk_bf16_f32 %0, %1, %2" : "=v"(w2) : "v"(b.x), "v"(b.y));
    asm("v_cvt_pk_bf16_f32 %0, %1, %2" : "=v"(w3) : "v"(b.z), "v"(b.w));
    u32x4 v = {w0, w1, w2, w3};
    return __builtin_bit_cast(bf16x8, v);
}

// ---------------- Kernel A: QKV projection via MFMA ----------------
// grid 750 blocks x 64 thr (1 wave = 32 x-rows). C = mfma(A=W, B=x^T):
// A rows = d (32 per dhalf), B cols = x-row, K=16 x 4 chained (j=0..63).
// Same operand/crow() conventions as the attn kernel (m74/m101-verified).
// Bias preloaded into the accumulator (MFMA C-in).
__global__ __launch_bounds__(64) void qkv_kernel(
    const float* __restrict__ x,
    const float* __restrict__ Wq, const float* __restrict__ bq,
    const float* __restrict__ Wk, const float* __restrict__ bk,
    const float* __restrict__ Wv, const float* __restrict__ bv,
    uint16_t* __restrict__ qbh, uint16_t* __restrict__ kbh,
    uint16_t* __restrict__ vbh)
{
    int lane = threadIdx.x;
    int ln31 = lane & 31, hi = lane >> 5;
    int row  = blockIdx.x * 32 + ln31;      // 750*32 = 24000 rows
    int bt   = row / 250;
    int nn   = row - bt*250;

    // B-frags: x[row][j], k = jf*16 + hi*8 + 0..7 (col = row, per attn conv.)
    bf16x8 xf[4];
    #pragma unroll
    for (int jf = 0; jf < 4; ++jf)
        xf[jf] = pack8(x + (size_t)row*64 + jf*16 + hi*8);

    const float* Wp[3] = {Wq, Wk, Wv};
    const float* bp[3] = {bq, bk, bv};

    #pragma unroll
    for (int w = 0; w < 3; ++w) {
        #pragma unroll
        for (int dhalf = 0; dhalf < 2; ++dhalf) {
            // A-frags: W[dbase+ln31][j], same k split
            bf16x8 af[4];
            #pragma unroll
            for (int jf = 0; jf < 4; ++jf)
                af[jf] = pack8(Wp[w] + (size_t)(dhalf*32 + ln31)*64 + jf*16 + hi*8);

            f32x16 acc;
            #pragma unroll
            for (int reg = 0; reg < 16; ++reg) {
                int d = dhalf*32 + (reg & 3) + 8*(reg >> 2) + 4*hi;
                acc[reg] = bp[w][d];
            }
            #pragma unroll
            for (int jf = 0; jf < 4; ++jf)
                acc = __builtin_amdgcn_mfma_f32_32x32x16_bf16(af[jf], xf[jf], acc, 0, 0, 0);

            #pragma unroll
            for (int reg = 0; reg < 16; ++reg) {
                int d  = dhalf*32 + (reg & 3) + 8*(reg >> 2) + 4*hi;
                int h  = d >> 3, dh = d & 7;
                uint16_t val = f2bf(acc[reg]);
                if (w == 0)
                    qbh[((size_t)(bt*8 + h)*256 + nn)*8 + dh] = val;
                else if (w == 1)
                    kbh[((size_t)(bt*8 + h)*256 + nn)*8 + dh] = val;
                else
                    vbh[((size_t)(bt*8 + h)*8 + dh)*256 + nn] = val;
            }
        }
    }
}

// ---------------- Kernel B: MFMA windowed attention (best-measured config) --
// grid = (b,t,ti,ntile) = 2304 blocks x 512 thr (8 waves; wave = head h).
// f32 adj tile in LDS (stride 260), launch_bounds(512,4). Q pre-scaled by
// scale*log2e. hs output bf16. K prologue hoisted before the barrier.
__global__ __launch_bounds__(512, 4) void attn_kernel(
    const uint16_t* __restrict__ qbh, const uint16_t* __restrict__ kbh,
    const uint16_t* __restrict__ vbh, const float* __restrict__ adj,
    uint16_t* __restrict__ hs)
{
    __shared__ float alds[32*260];     // [n-local][m], pad 260 for b128 reads

    const float S0e = 0.51006972338f;    // 8^-0.5 * log2(e)
    const float S1e = 0.18033688011f;    // 8^-1   * log2(e)
    const float S2e = 0.06375872168f;    // 8^-1.5 * log2(e)

    int tid  = threadIdx.x;
    int h    = tid >> 6;          // wave id = head
    int lane = tid & 63;
    int ln31 = lane & 31, hi = lane >> 5;

    int idx = blockIdx.x;
    int ntile = idx & 7; idx >>= 3;
    int ti = idx % 3; idx /= 3;
    int t  = idx % 12;
    int b  = idx / 12;

    int t_k = (ti == 2) ? t : (t + 11) % 12;   // cumulative k/v shift
    int t_a = (t + ti + 11) % 12;              // fresh adj shift
    float scale = (ti == 0) ? S0e : (ti == 1) ? S1e : S2e;

    int n0 = ntile * 32;

    // ---- stage adj tile: rows n0..n0+31 (clamped), cols 0..255 (m-pad=0) --
    const float* adjs = adj + (size_t)(b*12 + t_a) * 62500;
    for (int i = tid; i < 8192; i += 512) {
        int row = i >> 8;            // 0..31
        int col = i & 255;           // 0..255
        int nr = n0 + row; nr = nr > 249 ? 249 : nr;
        float v = (col < 250) ? adjs[(size_t)nr*250 + col] : 0.f;
        alds[row*260 + col] = v;
    }

    const uint16_t* qh = qbh + ((size_t)((b*12 + t  )*8 + h) * 256) * 8;
    const uint16_t* kh = kbh + ((size_t)((b*12 + t_k)*8 + h) * 256) * 8;
    const uint16_t* vh = vbh + ((size_t)((b*12 + t_k)*8 + h) * 8) * 256;

    int n  = n0 + ln31;

    bf16x8 qf = *(const bf16x8*)(qh + (size_t)n * 8);
    bf16x8 z8 = {0,0,0,0,0,0,0,0};
    if (hi) qf = z8;               // zeroes QK k=8..15 (B-operand side)

    // pre-scale Q by scale (incl. log2e)
    {
        const uint16_t* qu = (const uint16_t*)&qf;
        unsigned qw[4];
        #pragma unroll
        for (int e = 0; e < 4; ++e) {
            float q0 = __builtin_bit_cast(float, (uint32_t)qu[2*e]   << 16) * scale;
            float q1 = __builtin_bit_cast(float, (uint32_t)qu[2*e+1] << 16) * scale;
            asm("v_cvt_pk_bf16_f32 %0, %1, %2" : "=v"(qw[e]) : "v"(q0), "v"(q1));
        }
        u32x4 qv = {qw[0], qw[1], qw[2], qw[3]};
        qf = __builtin_bit_cast(bf16x8, qv);
    }

    const uint16_t* vrp = vh + (size_t)(ln31 & 7) * 256;
    const float* arow_l = &alds[ln31*260 + 4*hi];

    f32x16 zc;
    #pragma unroll
    for (int i = 0; i < 16; ++i) zc[i] = 0.f;
    f32x16 acc = zc;
    float zA = 0.f, zB = 0.f;         // split Z chain

    // score pipeline prologue BEFORE the barrier (no LDS dependency)
    bf16x8 kf0 = *(const bf16x8*)(kh + (size_t)ln31 * 8);
    f32x16 s_c = __builtin_amdgcn_mfma_f32_32x32x16_bf16(kf0, qf, zc, 0, 0, 0);

    __syncthreads();                  // adj staging visible

    #pragma unroll
    for (int mt = 0; mt < 8; ++mt) {
        int m0 = mt * 32;

        bf16x8 kf_n = z8;
        if (mt < 7)
            kf_n = *(const bf16x8*)(kh + (size_t)(m0 + 32 + ln31) * 8);

        bf16x8 vfa = *(const bf16x8*)(vrp + m0 + hi*8);
        bf16x8 vfb = *(const bf16x8*)(vrp + m0 + 16 + hi*8);

        f32x4v av0 = *(const f32x4v*)(arow_l + m0);
        f32x4v av1 = *(const f32x4v*)(arow_l + m0 + 8);
        f32x4v av2 = *(const f32x4v*)(arow_l + m0 + 16);
        f32x4v av3 = *(const f32x4v*)(arow_l + m0 + 24);

        unsigned w[8];
        #pragma unroll
        for (int e = 0; e < 8; ++e) {
            int r0 = 2*e, r1 = 2*e + 1;
            float p0 = EXP2(s_c[r0]);        // scale pre-folded into Q
            float p1 = EXP2(s_c[r1]);
            float av0v = (r0 < 4) ? av0[r0 & 3] : (r0 < 8) ? av1[r0 & 3]
                       : (r0 < 12) ? av2[r0 & 3] : av3[r0 & 3];
            float av1v = (r1 < 4) ? av0[r1 & 3] : (r1 < 8) ? av1[r1 & 3]
                       : (r1 < 12) ? av2[r1 & 3] : av3[r1 & 3];
            if (mt == 7) {   // zero p for m-pad 250..255 (av already 0 in LDS)
                int c0 = (r0 & 3) + 8*(r0 >> 2) + 4*hi;
                int c1 = (r1 & 3) + 8*(r1 >> 2) + 4*hi;
                if (224 + c0 >= 250) p0 = 0.f;
                if (224 + c1 >= 250) p1 = 0.f;
            }
            zA += p0; zB += p1;
            float pa0 = p0 * av0v, pa1 = p1 * av1v;
            asm("v_cvt_pk_bf16_f32 %0, %1, %2"
                : "=v"(w[e]) : "v"(pa0), "v"(pa1));
        }
        asm("v_permlane32_swap_b32 %0, %1" : "+v"(w[2]), "+v"(w[0]));
        asm("v_permlane32_swap_b32 %0, %1" : "+v"(w[3]), "+v"(w[1]));
        asm("v_permlane32_swap_b32 %0, %1" : "+v"(w[6]), "+v"(w[4]));
        asm("v_permlane32_swap_b32 %0, %1" : "+v"(w[7]), "+v"(w[5]));

        u32x4 t1 = {w[0], w[1], w[2], w[3]};
        u32x4 t2 = {w[4], w[5], w[6], w[7]};
        bf16x8 pf1 = __builtin_bit_cast(bf16x8, t1);
        bf16x8 pf2 = __builtin_bit_cast(bf16x8, t2);

        f32x16 s_n = s_c;
        if (mt < 7)
            s_n = __builtin_amdgcn_mfma_f32_32x32x16_bf16(kf_n, qf, zc, 0, 0, 0);

        acc = __builtin_amdgcn_mfma_f32_32x32x16_bf16(vfa, pf1, acc, 0, 0, 0);
        acc = __builtin_amdgcn_mfma_f32_32x32x16_bf16(vfb, pf2, acc, 0, 0, 0);

        s_c = s_n;
    }

    float z = zA + zB;
    float zf = z + __shfl_xor(z, 32);
    float inv = 1.0f / zf;

    if (n < 250) {
        float a0 = acc[0]*inv, a1 = acc[1]*inv;
        float a2 = acc[2]*inv, a3 = acc[3]*inv;
        unsigned w0, w1;
        asm("v_cvt_pk_bf16_f32 %0, %1, %2" : "=v"(w0) : "v"(a0), "v"(a1));
        asm("v_cvt_pk_bf16_f32 %0, %1, %2" : "=v"(w1) : "v"(a2), "v"(a3));
        u32x2 pk = {w0, w1};
        *(u32x2*)(hs + (((size_t)(b*36 + ti*12 + t)*250 + n)*64 + h*8 + hi*4)) = pk;
    }
}

// ---------------- Kernel C: Wd head + residual + LayerNorm ----------------
// hs is bf16: staged as u32 pairs, unpacked to f32 in LDS.
__global__ __launch_bounds__(256) void out_kernel(
    const uint16_t* __restrict__ hsb, const float* __restrict__ x,
    const float* __restrict__ Wd, const float* __restrict__ bd,
    const float* __restrict__ gamma, const float* __restrict__ beta,
    float* __restrict__ out)
{
    __shared__ float hl[36*64];
    __shared__ float xl[12*64];

    int bn = blockIdx.x;
    int n = bn % 250, b = bn / 250;
    int tid = threadIdx.x;

    for (int i = tid; i < 36*32; i += 256) {    // 1152 u32 words (2 bf16 each)
        int tw = i >> 5;          // 0..35
        int dw = i & 31;          // d-pair index 0..31
        uint32_t g = *(const uint32_t*)(hsb +
            ((size_t)(b*36 + tw)*250 + n)*64 + dw*2);
        hl[tw*64 + 2*dw]     = bfLO(g);
        hl[tw*64 + 2*dw + 1] = bfHI(g);
    }
    for (int i = tid; i < 12*64; i += 256) {
        int t = i >> 6, d = i & 63;
        xl[i] = x[((size_t)(b*12 + t)*250 + n)*64 + d];
    }
    __syncthreads();

    int lane = tid & 63, wv = tid >> 6;
    float gg = gamma[lane], bb = beta[lane];

    for (int t = wv; t < 12; t += 4) {
        float acc = bd[t];
        const float* wd = Wd + t*36;
        #pragma unroll
        for (int tw = 0; tw < 36; ++tw)
            acc = fmaf(wd[tw], hl[tw*64 + lane], acc);
        float y = acc + xl[t*64 + lane];

        float s = y, s2 = y*y;
        #pragma unroll
        for (int o = 32; o >= 1; o >>= 1) {
            s  += __shfl_xor(s, o);
            s2 += __shfl_xor(s2, o);
        }
        float mu  = s * 0.015625f;
        float var = s2 * 0.015625f - mu*mu;
        out[((size_t)(b*12 + t)*250 + n)*64 + lane] =
            gg * (y - mu) * rsqrtf(var + 1e-5f) + bb;
    }
}

extern "C" void kernel_launch(void* const* d_in, const int* in_sizes, int n_in,
                              void* d_out, int out_size, void* d_ws, size_t ws_size,
                              hipStream_t stream)
{
    const float* x    = (const float*)d_in[0];
    // d_in[1] = ste : unused by the reference
    const float* adj  = (const float*)d_in[2];
    const float* Wq   = (const float*)d_in[3];
    const float* bq   = (const float*)d_in[4];
    const float* Wk   = (const float*)d_in[5];
    const float* bk   = (const float*)d_in[6];
    const float* Wv   = (const float*)d_in[7];
    const float* bv   = (const float*)d_in[8];
    const float* Wd   = (const float*)d_in[9];
    const float* bd   = (const float*)d_in[10];
    const float* gam  = (const float*)d_in[11];
    const float* bet  = (const float*)d_in[12];
    float* out = (float*)d_out;

    // ws layout (bytes): hs bf16 [9,216,000, region reserved 18,432,000] |
    // qbh | kbh | vbh (bf16, each 3,145,728 B).
    uint16_t* hs  = (uint16_t*)d_ws;
    uint16_t* qbh = (uint16_t*)((char*)d_ws + 18432000);
    uint16_t* kbh = qbh + 1572864;
    uint16_t* vbh = kbh + 1572864;

    qkv_kernel<<<750, 64, 0, stream>>>(x, Wq, bq, Wk, bk, Wv, bv, qbh, kbh, vbh);
    attn_kernel<<<B_*T_*3*8, 512, 0, stream>>>(qbh, kbh, vbh, adj, hs);
    out_kernel<<<B_*N_, 256, 0, stream>>>(hs, x, Wd, bd, gam, bet, out);
}